// Round 5
// baseline (2194.866 us; speedup 1.0000x reference)
//
#include <hip/hip_runtime.h>

#define BB 256
#define TT 100
#define HH 512
#define G4 2048
#define INL 176
#define KIN 192
#define NCAT 16
#define NCONT 48
#define VV 32
#define EE 8
#define MTOT (BB*TT)
#define GRPB 32   // j-blocks per m-group
#define NFLG (GRPB*4)   // per-wave flags per m-group

typedef unsigned short u16;
typedef unsigned int   u32;
typedef unsigned long long u64;
typedef __attribute__((ext_vector_type(8))) short bf16x8;
typedef __attribute__((ext_vector_type(4))) float f32x4;

__device__ __forceinline__ float bf2f(u16 u){
    union { u32 i; float f; } v; v.i = ((u32)u) << 16; return v.f;
}
__device__ __forceinline__ u16 f2bf(float f){
    union { float f; u32 i; } v; v.f = f;
    u32 b = v.i;
    b += 0x7FFFu + ((b >> 16) & 1u);   // round-to-nearest-even
    return (u16)(b >> 16);
}
// exact identity tanh(x) = 1 - 2/(e^{2x}+1); __expf precision << bf16 rounding
__device__ __forceinline__ float fast_tanh(float x){
    float e = __expf(2.f * x);
    return 1.f - 2.f / (e + 1.f);
}

// ---- canonical-name kernel: W_in fp32 [176][512] -> bf16 WinT [512][192] (pad) ----
__global__ void PredictionModel_58841051955204_kernel(
    const float* __restrict__ Win, u16* __restrict__ WinT){
    int idx = blockIdx.x*256 + threadIdx.x;
    if (idx >= HH*KIN) return;
    int h = idx / KIN, i = idx % KIN;
    WinT[idx] = (i < INL) ? f2bf(Win[i*HH + h]) : (u16)0;
}

// ---- bulk fp32 -> bf16 convert (weights) ----
__global__ void k_cvt(const float* __restrict__ in, u16* __restrict__ out, int n){
    int i = blockIdx.x*256 + threadIdx.x;
    if (i < n) out[i] = f2bf(in[i]);
}

// ---- featurize: fp32 inputs -> bf16 feat [25600][192] ----
__global__ void k_feat(const float* __restrict__ x, const float* __restrict__ mean,
                       const float* __restrict__ scale, const float* __restrict__ emb,
                       u16* __restrict__ feat){
    int idx = blockIdx.x*256 + threadIdx.x;
    int bt = idx >> 4, g = idx & 15;
    if (bt >= MTOT) return;
    const float* xr = x + (size_t)bt*64;
    u16* fr = feat + (size_t)bt*KIN;
    int k0 = g*4;
    int ci = (int)xr[k0];
    if (ci < 0) ci = 0;
    if (ci > VV-1) ci = VV-1;
    const float* ep = emb + (size_t)(g*VV + ci)*EE;
    int c0 = g*11;
    for (int e = 0; e < 8; e++) fr[c0+e] = f2bf(ep[e]);
    for (int j = 1; j <= 3; j++){
        int k = k0 + j;
        fr[c0 + 8 + (j-1)] = f2bf((xr[k] - mean[k]) / scale[k]);
    }
    fr[INL + g] = 0;
}

// ---- MFMA GEMM: out[m,n] = act(A(bf16) @ W(bf16 [N][K])^T + b1 + b2) ----
__global__ __launch_bounds__(256) void k_gemm(
    const u16* __restrict__ A, int lda,
    const u16* __restrict__ W, int K,
    const float* __restrict__ bias1, const float* __restrict__ bias2,
    void* __restrict__ out, int ldo, int kc_cnt, int do_relu, int out_half)
{
    __shared__ u16 sA[64*40];
    __shared__ u16 sB[256*40];
    int tid = threadIdx.x;
    int w = tid >> 6, lane = tid & 63, q = lane >> 4, r = lane & 15;
    int m0 = blockIdx.x * 64;
    int n0 = blockIdx.y * 256;

    f32x4 acc[4][4];
    for (int a_ = 0; a_ < 4; a_++)
        for (int b_ = 0; b_ < 4; b_++){
            acc[a_][b_][0] = 0.f; acc[a_][b_][1] = 0.f;
            acc[a_][b_][2] = 0.f; acc[a_][b_][3] = 0.f;
        }

    for (int kc = 0; kc < kc_cnt; kc++){
        {
            int row = tid >> 2, seg = tid & 3;
            uint4 v = *(const uint4*)(A + (size_t)(m0+row)*lda + kc*32 + seg*8);
            *(uint4*)(&sA[row*40 + seg*8]) = v;
            const u16* wr = W + (size_t)(n0 + tid)*K + kc*32;
            uint4 b0 = *(const uint4*)(wr);
            uint4 b1 = *(const uint4*)(wr+8);
            uint4 b2 = *(const uint4*)(wr+16);
            uint4 b3 = *(const uint4*)(wr+24);
            u16* d = &sB[tid*40];
            *(uint4*)(d)    = b0; *(uint4*)(d+8)  = b1;
            *(uint4*)(d+16) = b2; *(uint4*)(d+24) = b3;
        }
        __syncthreads();
        bf16x8 a[4], b[4];
        for (int mt = 0; mt < 4; mt++) a[mt] = *(const bf16x8*)(&sA[(mt*16 + r)*40 + q*8]);
        for (int i = 0; i < 4; i++)    b[i]  = *(const bf16x8*)(&sB[((w*4+i)*16 + r)*40 + q*8]);
        for (int mt = 0; mt < 4; mt++)
            for (int i = 0; i < 4; i++)
                acc[mt][i] = __builtin_amdgcn_mfma_f32_16x16x32_bf16(a[mt], b[i], acc[mt][i], 0, 0, 0);
        __syncthreads();
    }

    for (int i = 0; i < 4; i++){
        int n = n0 + (w*4+i)*16 + r;
        float bs = 0.f;
        if (bias1) bs += bias1[n];
        if (bias2) bs += bias2[n];
        for (int mt = 0; mt < 4; mt++){
            for (int reg = 0; reg < 4; reg++){
                int m = m0 + mt*16 + q*4 + reg;
                float v = acc[mt][i][reg] + bs;
                if (do_relu) v = fmaxf(v, 0.f);
                if (out_half) ((_Float16*)out)[(size_t)m*ldo + n] = (_Float16)v;
                else          ((u16*)out)[(size_t)m*ldo + n] = f2bf(v);
            }
        }
    }
}

// ---- zero barrier flags ----
__global__ void k_zcnt(int* bar){
    int i = blockIdx.x*256 + threadIdx.x;
    if (i < 4*NFLG*16) bar[i] = 0;
}

// ---- PERSISTENT recurrence v8: WAVE-granular flag barrier, zero in-loop syncthreads ----
// grid 128 = 4 m-groups x 32 j-blocks. Block: m0 = (bid&3)*64, j0 = (bid>>2)*16.
// Key fact: wave w consumes ONLY h-rows m0+w*16..+15 — produced by wave w of the
// other 31 j-blocks. So the barrier is wave-level: per-(jb,w) flags, each wave does
// its own vmcnt(0) drain -> flag store -> polls its 32 peers. No __syncthreads in
// the t-loop (LDS only touched pre-loop), no wave0-poll->broadcast serialization.
// xw gate-addends double-buffered: t+1's 16 HBM loads issued BEFORE the poll so
// HBM latency hides under the spin. h packed as u32 pairs (1 shuffle, not 3).
__global__ __launch_bounds__(256, 1) void k_rec_seq(
    const u16* __restrict__ Whhb,       // bf16 [2048][512] layer slice
    const _Float16* __restrict__ xw,    // [MTOT][2048], biases folded
    u64* __restrict__ h64A,             // [256][128] u64 (= bf16 [256][512])
    u64* __restrict__ h64B,
    u16* __restrict__ Xout,             // relu(h) sequence (layer 0) or null
    int* __restrict__ bar)
{
    __shared__ u16 sB[64*512];   // exactly 65536 B
    int tid = threadIdx.x;
    int w = tid >> 6, lane = tid & 63, q = lane >> 4, r = lane & 15;
    int mg = blockIdx.x & 3;
    int jb = blockIdx.x >> 2;
    int m0 = mg * 64;
    int j0 = jb * 16;
    int* flags = bar + mg * (NFLG*16);
    int myfl = ((jb << 2) | w) * 16;
    int j = j0 + r;

    {   // stage B once: row n (g=n>>4, jj=n&15) <- Whhb[g*512 + j0 + jj][:]
        int row = tid >> 2, seg = tid & 3;
        int g = row >> 4, jj = row & 15;
        const u16* src = Whhb + (size_t)(g*HH + j0 + jj)*HH;
        for (int i = 0; i < 16; i++){
            int c = seg*16 + i;
            *(uint4*)(&sB[row*512 + ((c ^ (row & 7)) * 8)]) = *(const uint4*)(src + c*8);
        }
    }
    // zero my hA cells (SC1 stores, visible after flag round t=-1)
    float creg[4] = {0.f, 0.f, 0.f, 0.f};
    if ((r & 3) == 0){
        for (int reg = 0; reg < 4; reg++){
            int m = m0 + w*16 + q*4 + reg;
            __hip_atomic_store(&h64A[(size_t)m*(HH/4) + ((j0 + r) >> 2)], 0ULL,
                               __ATOMIC_RELAXED, __HIP_MEMORY_SCOPE_AGENT);
        }
    }
    __syncthreads();   // sB staged before fragment preload (only sync in kernel)

    // preload ALL B fragments into registers (t-invariant)
    bf16x8 bfr[16][4];
    #pragma unroll
    for (int kc = 0; kc < 16; kc++){
        #pragma unroll
        for (int g = 0; g < 4; g++){
            int row = g*16 + r;
            bfr[kc][g] = *(const bf16x8*)(&sB[row*512 + (((kc*4 + q) ^ (row & 7)) * 8)]);
        }
    }

    // ---- arrive(t=-1): my zero-stores drained -> flag=1 ----
    asm volatile("s_waitcnt vmcnt(0)" ::: "memory");
    if (lane == 0)
        __hip_atomic_store(&flags[myfl], 1, __ATOMIC_RELAXED, __HIP_MEMORY_SCOPE_AGENT);

    // prefetch xw gate-addends for t=0 (overlaps initial poll)
    float xnxt[4][4];
    #pragma unroll
    for (int reg = 0; reg < 4; reg++){
        int m = m0 + w*16 + q*4 + reg;
        const _Float16* xr = xw + ((size_t)m*TT + 0)*G4 + j;
        #pragma unroll
        for (int g = 0; g < 4; g++)
            xnxt[reg][g] = (float)__builtin_nontemporal_load(xr + g*HH);
    }

    // wait for my 32 peer waves (same w, all jb) to arrive
    if (lane < GRPB){
        long long t0 = clock64();
        while (__hip_atomic_load(&flags[((lane << 2) | w) * 16], __ATOMIC_RELAXED,
                                 __HIP_MEMORY_SCOPE_AGENT) < 1){
            __builtin_amdgcn_s_sleep(1);
            if (clock64() - t0 > 50000000LL) break;   // watchdog: degrade, not hang
        }
    }
    asm volatile("" ::: "memory");   // no memory op crosses the poll

    for (int t = 0; t < TT; t++){
        const u64* hsrc = (t & 1) ? h64B : h64A;    // t=0 reads zeros in A
        u64*       hdst = (t & 1) ? h64A : h64B;    // t=99 writes A (final in hA)
        const u64* hrow = hsrc + (size_t)(m0 + w*16 + r)*(HH/4);

        // gate-addends for this step were prefetched last iteration
        float xcur[4][4];
        #pragma unroll
        for (int reg = 0; reg < 4; reg++)
            #pragma unroll
            for (int g = 0; g < 4; g++)
                xcur[reg][g] = xnxt[reg][g];

        // batch-issue ALL 32 u64 h-loads (one vmcnt window)
        u64 hd[32];
        #pragma unroll
        for (int kc = 0; kc < 16; kc++){
            int jg0 = kc*8 + q*2;
            hd[kc*2]   = __hip_atomic_load(&hrow[jg0],   __ATOMIC_RELAXED, __HIP_MEMORY_SCOPE_AGENT);
            hd[kc*2+1] = __hip_atomic_load(&hrow[jg0+1], __ATOMIC_RELAXED, __HIP_MEMORY_SCOPE_AGENT);
        }
        // prefetch xw for t+1 (independent of h; lands during MFMA/cell/spin)
        if (t + 1 < TT){
            #pragma unroll
            for (int reg = 0; reg < 4; reg++){
                int m = m0 + w*16 + q*4 + reg;
                const _Float16* xr = xw + ((size_t)m*TT + (t+1))*G4 + j;
                #pragma unroll
                for (int g = 0; g < 4; g++)
                    xnxt[reg][g] = (float)__builtin_nontemporal_load(xr + g*HH);
            }
        }
        // keep-alive fence: hd values live here; loads can't sink into MFMA loop
        asm volatile("" :
            "+v"(hd[0]),  "+v"(hd[1]),  "+v"(hd[2]),  "+v"(hd[3]),
            "+v"(hd[4]),  "+v"(hd[5]),  "+v"(hd[6]),  "+v"(hd[7]),
            "+v"(hd[8]),  "+v"(hd[9]),  "+v"(hd[10]), "+v"(hd[11]),
            "+v"(hd[12]), "+v"(hd[13]), "+v"(hd[14]), "+v"(hd[15]));
        asm volatile("" :
            "+v"(hd[16]), "+v"(hd[17]), "+v"(hd[18]), "+v"(hd[19]),
            "+v"(hd[20]), "+v"(hd[21]), "+v"(hd[22]), "+v"(hd[23]),
            "+v"(hd[24]), "+v"(hd[25]), "+v"(hd[26]), "+v"(hd[27]),
            "+v"(hd[28]), "+v"(hd[29]), "+v"(hd[30]), "+v"(hd[31]));
        __builtin_amdgcn_sched_barrier(0);

        f32x4 acc[4];
        for (int g = 0; g < 4; g++){
            acc[g][0] = 0.f; acc[g][1] = 0.f; acc[g][2] = 0.f; acc[g][3] = 0.f;
        }
        #pragma unroll
        for (int kc = 0; kc < 16; kc++){
            union { u64 d[2]; bf16x8 v; } au;
            au.d[0] = hd[kc*2];
            au.d[1] = hd[kc*2+1];
            #pragma unroll
            for (int g = 0; g < 4; g++)
                acc[g] = __builtin_amdgcn_mfma_f32_16x16x32_bf16(au.v, bfr[kc][g], acc[g], 0, 0, 0);
        }

        // cell update + SC1 h store (u32 pair via one shuffle)
        u32* hdst32 = (u32*)hdst;
        #pragma unroll
        for (int reg = 0; reg < 4; reg++){
            int m = m0 + w*16 + q*4 + reg;
            float Gi = acc[0][reg] + xcur[reg][0];
            float Gf = acc[1][reg] + xcur[reg][1];
            float Gg = acc[2][reg] + xcur[reg][2];
            float Go = acc[3][reg] + xcur[reg][3];
            float iv = 1.f/(1.f + __expf(-Gi));
            float fv = 1.f/(1.f + __expf(-Gf));
            float gv = fast_tanh(Gg);
            float ov = 1.f/(1.f + __expf(-Go));
            float c = fv * creg[reg] + iv * gv;
            creg[reg] = c;
            float h = ov * fast_tanh(c);
            u32 own = (u32)f2bf(h);
            u32 p01 = own | (((u32)__shfl_xor((int)own, 1)) << 16);  // (j, j+1) on even r
            if ((r & 1) == 0){
                __hip_atomic_store(&hdst32[(size_t)m*(HH/2) + ((j0 + r) >> 1)], p01,
                                   __ATOMIC_RELAXED, __HIP_MEMORY_SCOPE_AGENT);
            }
            if (Xout){
                size_t bt = (size_t)m*TT + t;
                __builtin_nontemporal_store(f2bf(fmaxf(h, 0.f)), Xout + bt*HH + j);
            }
        }

        // ---- per-wave arrive + wait ----
        asm volatile("s_waitcnt vmcnt(0)" ::: "memory");   // h stores globally visible
        if (lane == 0)
            __hip_atomic_store(&flags[myfl], t + 2, __ATOMIC_RELAXED,
                               __HIP_MEMORY_SCOPE_AGENT);
        if (t + 1 < TT){
            if (lane < GRPB){
                long long t0 = clock64();
                while (__hip_atomic_load(&flags[((lane << 2) | w) * 16], __ATOMIC_RELAXED,
                                         __HIP_MEMORY_SCOPE_AGENT) < t + 2){
                    __builtin_amdgcn_s_sleep(1);
                    if (clock64() - t0 > 50000000LL) break;   // watchdog
                }
            }
            asm volatile("" ::: "memory");   // h loads of t+1 stay below the poll
        }
    }
}

// ---- heads: fp32 output (d_out is float*), zero-sentinel kept ----
__global__ void k_heads(
    const u16* __restrict__ hfin, const float* __restrict__ Wout,
    const float* __restrict__ bout, const float* __restrict__ Wcls,
    const float* __restrict__ bcls, float* __restrict__ out)
{
    __shared__ float last[HH];
    int b = blockIdx.x, tid = threadIdx.x;
    for (int h = tid; h < HH; h += 256) last[h] = fmaxf(bf2f(hfin[b*HH + h]), 0.f);
    __syncthreads();
    for (int o = tid; o < NCONT + NCAT*VV; o += 256){
        if (o < NCONT){
            float a = bout[o];
            for (int h = 0; h < HH; h++) a += last[h] * Wout[h*NCONT + o];
            out[b*NCONT + o] = (a == 0.0f) ? 7.0f : a;
        } else {
            int oc = o - NCONT;
            int n = oc >> 5, v = oc & 31;
            float a = bcls[oc];
            const float* wp = Wcls + (size_t)n*HH*VV + v;
            for (int h = 0; h < HH; h++) a += last[h] * wp[h*VV];
            out[BB*NCONT + b*(NCAT*VV) + oc] = (a == 0.0f) ? 7.0f : a;
        }
    }
}

extern "C" void kernel_launch(void* const* d_in, const int* in_sizes, int n_in,
                              void* d_out, int out_size, void* d_ws, size_t ws_size,
                              hipStream_t stream){
    const float* x      = (const float*)d_in[0];
    const float* smean  = (const float*)d_in[1];
    const float* sscale = (const float*)d_in[2];
    const float* emb    = (const float*)d_in[3];
    const float* Win    = (const float*)d_in[4];
    const float* bin    = (const float*)d_in[5];
    const float* Wih    = (const float*)d_in[6];
    const float* Whh    = (const float*)d_in[7];
    const float* bih    = (const float*)d_in[8];
    const float* bhh    = (const float*)d_in[9];
    const float* Wout   = (const float*)d_in[10];
    const float* bout   = (const float*)d_in[11];
    const float* Wcls   = (const float*)d_in[12];
    const float* bcls   = (const float*)d_in[13];
    (void)in_sizes; (void)n_in; (void)out_size;

    char* ws = (char*)d_ws;
    size_t off = 0;
    u16*      feat  = (u16*)(ws + off);      off += (size_t)MTOT*KIN*2;   //   9.8 MB
    u16*      WinTb = (u16*)(ws + off);      off += (size_t)HH*KIN*2;     //   0.2 MB
    u16*      Xbuf  = (u16*)(ws + off);      off += (size_t)MTOT*HH*2;    //  26.2 MB
    _Float16* xw    = (_Float16*)(ws + off); off += (size_t)MTOT*G4*2;    // 104.9 MB
    u16*      Wihb  = (u16*)(ws + off);      off += (size_t)2*G4*HH*2;    //   4.2 MB
    u16*      Whhb  = (u16*)(ws + off);      off += (size_t)2*G4*HH*2;    //   4.2 MB
    u64*      hA    = (u64*)(ws + off);      off += (size_t)BB*HH*2;
    u64*      hB    = (u64*)(ws + off);      off += (size_t)BB*HH*2;
    int*      bar   = (int*)(ws + off);      off += 4*NFLG*16*4;          //  32 KB
    (void)off; (void)ws_size;

    // weight prep (bf16 once)
    PredictionModel_58841051955204_kernel<<<384, 256, 0, stream>>>(Win, WinTb);
    k_cvt<<<8192, 256, 0, stream>>>(Wih, Wihb, 2*G4*HH);
    k_cvt<<<8192, 256, 0, stream>>>(Whh, Whhb, 2*G4*HH);

    k_feat<<<1600, 256, 0, stream>>>(x, smean, sscale, emb, feat);
    // h0 = relu(feat @ W_in + b_in) -> Xbuf (bf16)
    k_gemm<<<dim3(400, 2), 256, 0, stream>>>(feat, KIN, WinTb, KIN, bin, (const float*)0,
                                             Xbuf, HH, 6, 1, 0);
    for (int l = 0; l < 2; l++){
        // xw = Xbuf @ Wih_l^T + bih_l + bhh_l -> fp16 (Xbuf consumed before rec overwrites it)
        k_gemm<<<dim3(400, 8), 256, 0, stream>>>(Xbuf, HH, Wihb + (size_t)l*G4*HH, HH,
                                                 bih + l*G4, bhh + l*G4,
                                                 xw, G4, 16, 0, 1);
        k_zcnt<<<32, 256, 0, stream>>>(bar);
        k_rec_seq<<<128, 256, 0, stream>>>(Whhb + (size_t)l*G4*HH, xw, hA, hB,
                                           (l == 0) ? Xbuf : (u16*)0, bar);
    }
    // T=100 even -> final h in hA; heads write fp32 d_out
    k_heads<<<256, 256, 0, stream>>>((const u16*)hA, Wout, bout, Wcls, bcls, (float*)d_out);
}

// Round 6
// 1407.391 us; speedup vs baseline: 1.5595x; 1.5595x over previous
//
#include <hip/hip_runtime.h>

#define BB 256
#define TT 100
#define HH 512
#define G4 2048
#define INL 176
#define KIN 192
#define NCAT 16
#define NCONT 48
#define VV 32
#define EE 8
#define MTOT (BB*TT)
#define GRPB 32   // j-blocks per m-group

typedef unsigned short u16;
typedef unsigned int   u32;
typedef unsigned long long u64;
typedef __attribute__((ext_vector_type(8))) short bf16x8;
typedef __attribute__((ext_vector_type(4))) float f32x4;

__device__ __forceinline__ float bf2f(u16 u){
    union { u32 i; float f; } v; v.i = ((u32)u) << 16; return v.f;
}
__device__ __forceinline__ u16 f2bf(float f){
    union { float f; u32 i; } v; v.f = f;
    u32 b = v.i;
    b += 0x7FFFu + ((b >> 16) & 1u);   // round-to-nearest-even
    return (u16)(b >> 16);
}
// exact identity tanh(x) = 1 - 2/(e^{2x}+1); __expf precision << bf16 rounding
__device__ __forceinline__ float fast_tanh(float x){
    float e = __expf(2.f * x);
    return 1.f - 2.f / (e + 1.f);
}

// ---- canonical-name kernel: W_in fp32 [176][512] -> bf16 WinT [512][192] (pad) ----
__global__ void PredictionModel_58841051955204_kernel(
    const float* __restrict__ Win, u16* __restrict__ WinT){
    int idx = blockIdx.x*256 + threadIdx.x;
    if (idx >= HH*KIN) return;
    int h = idx / KIN, i = idx % KIN;
    WinT[idx] = (i < INL) ? f2bf(Win[i*HH + h]) : (u16)0;
}

// ---- bulk fp32 -> bf16 convert (weights) ----
__global__ void k_cvt(const float* __restrict__ in, u16* __restrict__ out, int n){
    int i = blockIdx.x*256 + threadIdx.x;
    if (i < n) out[i] = f2bf(in[i]);
}

// ---- featurize: fp32 inputs -> bf16 feat [25600][192] ----
__global__ void k_feat(const float* __restrict__ x, const float* __restrict__ mean,
                       const float* __restrict__ scale, const float* __restrict__ emb,
                       u16* __restrict__ feat){
    int idx = blockIdx.x*256 + threadIdx.x;
    int bt = idx >> 4, g = idx & 15;
    if (bt >= MTOT) return;
    const float* xr = x + (size_t)bt*64;
    u16* fr = feat + (size_t)bt*KIN;
    int k0 = g*4;
    int ci = (int)xr[k0];
    if (ci < 0) ci = 0;
    if (ci > VV-1) ci = VV-1;
    const float* ep = emb + (size_t)(g*VV + ci)*EE;
    int c0 = g*11;
    for (int e = 0; e < 8; e++) fr[c0+e] = f2bf(ep[e]);
    for (int j = 1; j <= 3; j++){
        int k = k0 + j;
        fr[c0 + 8 + (j-1)] = f2bf((xr[k] - mean[k]) / scale[k]);
    }
    fr[INL + g] = 0;
}

// ---- MFMA GEMM: out[m,n] = act(A(bf16) @ W(bf16 [N][K])^T + b1 + b2) ----
__global__ __launch_bounds__(256) void k_gemm(
    const u16* __restrict__ A, int lda,
    const u16* __restrict__ W, int K,
    const float* __restrict__ bias1, const float* __restrict__ bias2,
    void* __restrict__ out, int ldo, int kc_cnt, int do_relu, int out_half)
{
    __shared__ u16 sA[64*40];
    __shared__ u16 sB[256*40];
    int tid = threadIdx.x;
    int w = tid >> 6, lane = tid & 63, q = lane >> 4, r = lane & 15;
    int m0 = blockIdx.x * 64;
    int n0 = blockIdx.y * 256;

    f32x4 acc[4][4];
    for (int a_ = 0; a_ < 4; a_++)
        for (int b_ = 0; b_ < 4; b_++){
            acc[a_][b_][0] = 0.f; acc[a_][b_][1] = 0.f;
            acc[a_][b_][2] = 0.f; acc[a_][b_][3] = 0.f;
        }

    for (int kc = 0; kc < kc_cnt; kc++){
        {
            int row = tid >> 2, seg = tid & 3;
            uint4 v = *(const uint4*)(A + (size_t)(m0+row)*lda + kc*32 + seg*8);
            *(uint4*)(&sA[row*40 + seg*8]) = v;
            const u16* wr = W + (size_t)(n0 + tid)*K + kc*32;
            uint4 b0 = *(const uint4*)(wr);
            uint4 b1 = *(const uint4*)(wr+8);
            uint4 b2 = *(const uint4*)(wr+16);
            uint4 b3 = *(const uint4*)(wr+24);
            u16* d = &sB[tid*40];
            *(uint4*)(d)    = b0; *(uint4*)(d+8)  = b1;
            *(uint4*)(d+16) = b2; *(uint4*)(d+24) = b3;
        }
        __syncthreads();
        bf16x8 a[4], b[4];
        for (int mt = 0; mt < 4; mt++) a[mt] = *(const bf16x8*)(&sA[(mt*16 + r)*40 + q*8]);
        for (int i = 0; i < 4; i++)    b[i]  = *(const bf16x8*)(&sB[((w*4+i)*16 + r)*40 + q*8]);
        for (int mt = 0; mt < 4; mt++)
            for (int i = 0; i < 4; i++)
                acc[mt][i] = __builtin_amdgcn_mfma_f32_16x16x32_bf16(a[mt], b[i], acc[mt][i], 0, 0, 0);
        __syncthreads();
    }

    for (int i = 0; i < 4; i++){
        int n = n0 + (w*4+i)*16 + r;
        float bs = 0.f;
        if (bias1) bs += bias1[n];
        if (bias2) bs += bias2[n];
        for (int mt = 0; mt < 4; mt++){
            for (int reg = 0; reg < 4; reg++){
                int m = m0 + mt*16 + q*4 + reg;
                float v = acc[mt][i][reg] + bs;
                if (do_relu) v = fmaxf(v, 0.f);
                if (out_half) ((_Float16*)out)[(size_t)m*ldo + n] = (_Float16)v;
                else          ((u16*)out)[(size_t)m*ldo + n] = f2bf(v);
            }
        }
    }
}

// ---- zero barrier flags (two groups: F0, F1) ----
__global__ void k_zcnt(int* bar){
    int i = blockIdx.x*256 + threadIdx.x;
    if (i < 2*4*GRPB*16) bar[i] = 0;
}

// ---- FUSED two-layer recurrence v9 ----
// grid 256 = 2 layers x (4 m-groups x 32 j-blocks). 1 block/CU (128KB LDS).
// Layer 0 (bid<128): h0 recurrence (Whh0 in LDS), xw addends precomputed, publishes
//   BOTH h0(t) (pre-relu, own ping-pong) and relu(h0(t)) into a depth-4 ring x0r.
// Layer 1 (bid>=128): runs with 1-step skew; computes gates IN-KERNEL as
//   relu_h0(t) @ Wih1^T + h1(t-1) @ Whh1^T + bias (both K=512 from 128KB LDS).
// Critical path: 101 sync rounds instead of 200 + an extra 54-GFLOP GEMM.
// Flags: F0/F1 per (m-group, j-block), block-granular barrier (v5 style — v8's
// wave-granular polling contended the coherence point and regressed).
// Back-pressure: L0 also waits F1 >= t-1 (ring overwrite 3-round slack; never
// binds at steady skew 1-2). Dependency DAG L0(t)->L1(t-1)->L0(t-1): no cycle.
__global__ __launch_bounds__(256, 1) void k_rec2(
    const u16* __restrict__ Whhb,      // bf16 [2][2048][512]
    const u16* __restrict__ Wihb1,     // bf16 [2048][512] layer-1 slice
    const _Float16* __restrict__ xw,   // [MTOT][2048] layer-0 addends (biases folded)
    const float* __restrict__ bih, const float* __restrict__ bhh,  // [2][2048]
    u64* __restrict__ h0A, u64* __restrict__ h0B,
    u64* __restrict__ x0r,             // [4][256][128] u64 ring (relu'd h0, bf16)
    u64* __restrict__ h1A, u64* __restrict__ h1B,
    int* __restrict__ bar)
{
    extern __shared__ u16 smem[];      // 131072 B dynamic
    int tid = threadIdx.x;
    int w = tid >> 6, lane = tid & 63, q = lane >> 4, r = lane & 15;
    int lay  = blockIdx.x >> 7;
    int bid7 = blockIdx.x & 127;
    int mg = bid7 & 3, jb = bid7 >> 2;
    int m0 = mg*64, j0 = jb*16;
    int j = j0 + r;
    int* F0 = bar + mg*(GRPB*16);
    int* F1 = bar + 4*(GRPB*16) + mg*(GRPB*16);

    {   // stage weights: Whh slice (and Wih slice for layer 1), XOR-swizzled
        int row = tid >> 2, seg = tid & 3;
        int g = row >> 4, jj = row & 15;
        const u16* srcW = Whhb + (size_t)lay*G4*HH + (size_t)(g*HH + j0 + jj)*HH;
        u16* sW = smem + (lay ? 64*512 : 0);
        for (int i = 0; i < 16; i++){
            int c = seg*16 + i;
            *(uint4*)(&sW[row*512 + ((c ^ (row & 7)) * 8)]) = *(const uint4*)(srcW + c*8);
        }
        if (lay){
            const u16* srcI = Wihb1 + (size_t)(g*HH + j0 + jj)*HH;
            for (int i = 0; i < 16; i++){
                int c = seg*16 + i;
                *(uint4*)(&smem[row*512 + ((c ^ (row & 7)) * 8)]) = *(const uint4*)(srcI + c*8);
            }
        }
    }
    // zero my h cells in the t=0 source buffer (SC1, visible after round -1)
    float creg[4] = {0.f, 0.f, 0.f, 0.f};
    {
        u64* hz = lay ? h1A : h0A;
        if ((r & 3) == 0){
            for (int reg = 0; reg < 4; reg++){
                int m = m0 + w*16 + q*4 + reg;
                __hip_atomic_store(&hz[(size_t)m*(HH/4) + ((j0 + r) >> 2)], 0ULL,
                                   __ATOMIC_RELAXED, __HIP_MEMORY_SCOPE_AGENT);
            }
        }
    }
    // layer-1 bias (fp32, per gate column; shared by all 4 m-regs)
    float bs1[4] = {0.f, 0.f, 0.f, 0.f};
    if (lay){
        for (int g = 0; g < 4; g++)
            bs1[g] = bih[G4 + g*HH + j] + bhh[G4 + g*HH + j];
    }
    // layer-0 xw prefetch for t=0
    float xnxt[4][4];
    if (!lay){
        #pragma unroll
        for (int reg = 0; reg < 4; reg++){
            int m = m0 + w*16 + q*4 + reg;
            const _Float16* xr = xw + ((size_t)m*TT + 0)*G4 + j;
            #pragma unroll
            for (int g = 0; g < 4; g++)
                xnxt[reg][g] = (float)__builtin_nontemporal_load(xr + g*HH);
        }
    }

    for (int t = -1; t < TT; t++){
        if (t >= 0 && !lay){
            // =================== layer 0, round t ===================
            const u64* hsrc = (t & 1) ? h0B : h0A;
            u64*       hdst = (t & 1) ? h0A : h0B;
            u32* xdst32 = (u32*)(x0r + (size_t)(t & 3)*BB*(HH/4));
            const u64* hrow = hsrc + (size_t)(m0 + w*16 + r)*(HH/4);

            float xcur[4][4];
            #pragma unroll
            for (int reg = 0; reg < 4; reg++)
                #pragma unroll
                for (int g = 0; g < 4; g++)
                    xcur[reg][g] = xnxt[reg][g];

            u64 hd[32];
            #pragma unroll
            for (int kc = 0; kc < 16; kc++){
                int jg0 = kc*8 + q*2;
                hd[kc*2]   = __hip_atomic_load(&hrow[jg0],   __ATOMIC_RELAXED, __HIP_MEMORY_SCOPE_AGENT);
                hd[kc*2+1] = __hip_atomic_load(&hrow[jg0+1], __ATOMIC_RELAXED, __HIP_MEMORY_SCOPE_AGENT);
            }
            // prefetch xw for t+1 (hides under MFMA/cell/spin)
            if (t + 1 < TT){
                #pragma unroll
                for (int reg = 0; reg < 4; reg++){
                    int m = m0 + w*16 + q*4 + reg;
                    const _Float16* xr = xw + ((size_t)m*TT + (t+1))*G4 + j;
                    #pragma unroll
                    for (int g = 0; g < 4; g++)
                        xnxt[reg][g] = (float)__builtin_nontemporal_load(xr + g*HH);
                }
            }
            asm volatile("" :
                "+v"(hd[0]),  "+v"(hd[1]),  "+v"(hd[2]),  "+v"(hd[3]),
                "+v"(hd[4]),  "+v"(hd[5]),  "+v"(hd[6]),  "+v"(hd[7]),
                "+v"(hd[8]),  "+v"(hd[9]),  "+v"(hd[10]), "+v"(hd[11]),
                "+v"(hd[12]), "+v"(hd[13]), "+v"(hd[14]), "+v"(hd[15]));
            asm volatile("" :
                "+v"(hd[16]), "+v"(hd[17]), "+v"(hd[18]), "+v"(hd[19]),
                "+v"(hd[20]), "+v"(hd[21]), "+v"(hd[22]), "+v"(hd[23]),
                "+v"(hd[24]), "+v"(hd[25]), "+v"(hd[26]), "+v"(hd[27]),
                "+v"(hd[28]), "+v"(hd[29]), "+v"(hd[30]), "+v"(hd[31]));
            __builtin_amdgcn_sched_barrier(0);

            f32x4 acc[4];
            for (int g = 0; g < 4; g++){
                acc[g][0] = 0.f; acc[g][1] = 0.f; acc[g][2] = 0.f; acc[g][3] = 0.f;
            }
            #pragma unroll
            for (int kc = 0; kc < 16; kc++){
                union { u64 d[2]; bf16x8 v; } au;
                au.d[0] = hd[kc*2];
                au.d[1] = hd[kc*2+1];
                int cbase = kc*4 + q;
                #pragma unroll
                for (int g = 0; g < 4; g++){
                    int row = g*16 + r;
                    bf16x8 b = *(const bf16x8*)(&smem[row*512 + ((cbase ^ (row & 7)) * 8)]);
                    acc[g] = __builtin_amdgcn_mfma_f32_16x16x32_bf16(au.v, b, acc[g], 0, 0, 0);
                }
            }

            u32* hdst32 = (u32*)hdst;
            #pragma unroll
            for (int reg = 0; reg < 4; reg++){
                int m = m0 + w*16 + q*4 + reg;
                float Gi = acc[0][reg] + xcur[reg][0];
                float Gf = acc[1][reg] + xcur[reg][1];
                float Gg = acc[2][reg] + xcur[reg][2];
                float Go = acc[3][reg] + xcur[reg][3];
                float iv = 1.f/(1.f + __expf(-Gi));
                float fv = 1.f/(1.f + __expf(-Gf));
                float gv = fast_tanh(Gg);
                float ov = 1.f/(1.f + __expf(-Go));
                float c = fv * creg[reg] + iv * gv;
                creg[reg] = c;
                float h = ov * fast_tanh(c);
                u32 own  = (u32)f2bf(h);
                u32 ownr = (u32)f2bf(fmaxf(h, 0.f));
                u32 p01  = own  | (((u32)__shfl_xor((int)own,  1)) << 16);
                u32 pr01 = ownr | (((u32)__shfl_xor((int)ownr, 1)) << 16);
                if ((r & 1) == 0){
                    size_t ofs = (size_t)m*(HH/2) + ((j0 + r) >> 1);
                    __hip_atomic_store(&hdst32[ofs], p01, __ATOMIC_RELAXED, __HIP_MEMORY_SCOPE_AGENT);
                    __hip_atomic_store(&xdst32[ofs], pr01, __ATOMIC_RELAXED, __HIP_MEMORY_SCOPE_AGENT);
                }
            }
        } else if (t >= 0 && lay){
            // =================== layer 1, round t ===================
            const u64* xsrc = x0r + (size_t)(t & 3)*BB*(HH/4);
            const u64* hsrc = (t & 1) ? h1B : h1A;
            u64*       hdst = (t & 1) ? h1A : h1B;
            const u64* xrow = xsrc + (size_t)(m0 + w*16 + r)*(HH/4);
            const u64* hrow = hsrc + (size_t)(m0 + w*16 + r)*(HH/4);
            const u16* sWih = smem;
            const u16* sWhh = smem + 64*512;

            u64 hx[32], hh[32];
            #pragma unroll
            for (int kc = 0; kc < 16; kc++){
                int jg0 = kc*8 + q*2;
                hx[kc*2]   = __hip_atomic_load(&xrow[jg0],   __ATOMIC_RELAXED, __HIP_MEMORY_SCOPE_AGENT);
                hx[kc*2+1] = __hip_atomic_load(&xrow[jg0+1], __ATOMIC_RELAXED, __HIP_MEMORY_SCOPE_AGENT);
            }
            #pragma unroll
            for (int kc = 0; kc < 16; kc++){
                int jg0 = kc*8 + q*2;
                hh[kc*2]   = __hip_atomic_load(&hrow[jg0],   __ATOMIC_RELAXED, __HIP_MEMORY_SCOPE_AGENT);
                hh[kc*2+1] = __hip_atomic_load(&hrow[jg0+1], __ATOMIC_RELAXED, __HIP_MEMORY_SCOPE_AGENT);
            }
            asm volatile("" :
                "+v"(hx[0]),  "+v"(hx[1]),  "+v"(hx[2]),  "+v"(hx[3]),
                "+v"(hx[4]),  "+v"(hx[5]),  "+v"(hx[6]),  "+v"(hx[7]),
                "+v"(hx[8]),  "+v"(hx[9]),  "+v"(hx[10]), "+v"(hx[11]),
                "+v"(hx[12]), "+v"(hx[13]), "+v"(hx[14]), "+v"(hx[15]));
            asm volatile("" :
                "+v"(hx[16]), "+v"(hx[17]), "+v"(hx[18]), "+v"(hx[19]),
                "+v"(hx[20]), "+v"(hx[21]), "+v"(hx[22]), "+v"(hx[23]),
                "+v"(hx[24]), "+v"(hx[25]), "+v"(hx[26]), "+v"(hx[27]),
                "+v"(hx[28]), "+v"(hx[29]), "+v"(hx[30]), "+v"(hx[31]));
            __builtin_amdgcn_sched_barrier(0);

            f32x4 acc[4];
            for (int g = 0; g < 4; g++){
                acc[g][0] = 0.f; acc[g][1] = 0.f; acc[g][2] = 0.f; acc[g][3] = 0.f;
            }
            #pragma unroll
            for (int kc = 0; kc < 16; kc++){
                union { u64 d[2]; bf16x8 v; } au;
                au.d[0] = hx[kc*2];
                au.d[1] = hx[kc*2+1];
                int cbase = kc*4 + q;
                #pragma unroll
                for (int g = 0; g < 4; g++){
                    int row = g*16 + r;
                    bf16x8 b = *(const bf16x8*)(&sWih[row*512 + ((cbase ^ (row & 7)) * 8)]);
                    acc[g] = __builtin_amdgcn_mfma_f32_16x16x32_bf16(au.v, b, acc[g], 0, 0, 0);
                }
            }
            asm volatile("" :
                "+v"(hh[0]),  "+v"(hh[1]),  "+v"(hh[2]),  "+v"(hh[3]),
                "+v"(hh[4]),  "+v"(hh[5]),  "+v"(hh[6]),  "+v"(hh[7]),
                "+v"(hh[8]),  "+v"(hh[9]),  "+v"(hh[10]), "+v"(hh[11]),
                "+v"(hh[12]), "+v"(hh[13]), "+v"(hh[14]), "+v"(hh[15]));
            asm volatile("" :
                "+v"(hh[16]), "+v"(hh[17]), "+v"(hh[18]), "+v"(hh[19]),
                "+v"(hh[20]), "+v"(hh[21]), "+v"(hh[22]), "+v"(hh[23]),
                "+v"(hh[24]), "+v"(hh[25]), "+v"(hh[26]), "+v"(hh[27]),
                "+v"(hh[28]), "+v"(hh[29]), "+v"(hh[30]), "+v"(hh[31]));
            #pragma unroll
            for (int kc = 0; kc < 16; kc++){
                union { u64 d[2]; bf16x8 v; } au;
                au.d[0] = hh[kc*2];
                au.d[1] = hh[kc*2+1];
                int cbase = kc*4 + q;
                #pragma unroll
                for (int g = 0; g < 4; g++){
                    int row = g*16 + r;
                    bf16x8 b = *(const bf16x8*)(&sWhh[row*512 + ((cbase ^ (row & 7)) * 8)]);
                    acc[g] = __builtin_amdgcn_mfma_f32_16x16x32_bf16(au.v, b, acc[g], 0, 0, 0);
                }
            }

            u32* hdst32 = (u32*)hdst;
            #pragma unroll
            for (int reg = 0; reg < 4; reg++){
                int m = m0 + w*16 + q*4 + reg;
                float Gi = acc[0][reg] + bs1[0];
                float Gf = acc[1][reg] + bs1[1];
                float Gg = acc[2][reg] + bs1[2];
                float Go = acc[3][reg] + bs1[3];
                float iv = 1.f/(1.f + __expf(-Gi));
                float fv = 1.f/(1.f + __expf(-Gf));
                float gv = fast_tanh(Gg);
                float ov = 1.f/(1.f + __expf(-Go));
                float c = fv * creg[reg] + iv * gv;
                creg[reg] = c;
                float h = ov * fast_tanh(c);
                u32 own = (u32)f2bf(h);
                u32 p01 = own | (((u32)__shfl_xor((int)own, 1)) << 16);
                if ((r & 1) == 0){
                    __hip_atomic_store(&hdst32[(size_t)m*(HH/2) + ((j0 + r) >> 1)], p01,
                                       __ATOMIC_RELAXED, __HIP_MEMORY_SCOPE_AGENT);
                }
            }
        }

        // ---- block-granular barrier (v5 structure) ----
        __syncthreads();   // drains vmcnt(0): all SC1 stores retired => visible
        if (tid == 0){
            int* my = lay ? &F1[jb*16] : &F0[jb*16];
            __hip_atomic_store(my, t + 2, __ATOMIC_RELAXED, __HIP_MEMORY_SCOPE_AGENT);
        }
        if (t + 1 < TT){
            if (tid < 64){
                int* fp; int thr;
                if (!lay){
                    if (lane < GRPB){ fp = &F0[lane*16];          thr = t + 2; }  // peers
                    else            { fp = &F1[(lane-GRPB)*16];   thr = t - 1; }  // ring slack
                } else {
                    if (lane < GRPB){ fp = &F1[lane*16];          thr = t + 2; }  // peers
                    else            { fp = &F0[(lane-GRPB)*16];   thr = t + 3; }  // x0(t+1) ready
                }
                long long t0c = clock64();
                while (__hip_atomic_load(fp, __ATOMIC_RELAXED, __HIP_MEMORY_SCOPE_AGENT) < thr){
                    __builtin_amdgcn_s_sleep(1);
                    if (clock64() - t0c > 50000000LL) break;   // watchdog: degrade, not hang
                }
            }
            __syncthreads();
        }
    }
}

// ---- heads: fp32 output (d_out is float*), zero-sentinel kept ----
__global__ void k_heads(
    const u16* __restrict__ hfin, const float* __restrict__ Wout,
    const float* __restrict__ bout, const float* __restrict__ Wcls,
    const float* __restrict__ bcls, float* __restrict__ out)
{
    __shared__ float last[HH];
    int b = blockIdx.x, tid = threadIdx.x;
    for (int h = tid; h < HH; h += 256) last[h] = fmaxf(bf2f(hfin[b*HH + h]), 0.f);
    __syncthreads();
    for (int o = tid; o < NCONT + NCAT*VV; o += 256){
        if (o < NCONT){
            float a = bout[o];
            for (int h = 0; h < HH; h++) a += last[h] * Wout[h*NCONT + o];
            out[b*NCONT + o] = (a == 0.0f) ? 7.0f : a;
        } else {
            int oc = o - NCONT;
            int n = oc >> 5, v = oc & 31;
            float a = bcls[oc];
            const float* wp = Wcls + (size_t)n*HH*VV + v;
            for (int h = 0; h < HH; h++) a += last[h] * wp[h*VV];
            out[BB*NCONT + b*(NCAT*VV) + oc] = (a == 0.0f) ? 7.0f : a;
        }
    }
}

extern "C" void kernel_launch(void* const* d_in, const int* in_sizes, int n_in,
                              void* d_out, int out_size, void* d_ws, size_t ws_size,
                              hipStream_t stream){
    const float* x      = (const float*)d_in[0];
    const float* smean  = (const float*)d_in[1];
    const float* sscale = (const float*)d_in[2];
    const float* emb    = (const float*)d_in[3];
    const float* Win    = (const float*)d_in[4];
    const float* bin    = (const float*)d_in[5];
    const float* Wih    = (const float*)d_in[6];
    const float* Whh    = (const float*)d_in[7];
    const float* bih    = (const float*)d_in[8];
    const float* bhh    = (const float*)d_in[9];
    const float* Wout   = (const float*)d_in[10];
    const float* bout   = (const float*)d_in[11];
    const float* Wcls   = (const float*)d_in[12];
    const float* bcls   = (const float*)d_in[13];
    (void)in_sizes; (void)n_in; (void)out_size;

    char* ws = (char*)d_ws;
    size_t off = 0;
    u16*      feat  = (u16*)(ws + off);      off += (size_t)MTOT*KIN*2;   //   9.8 MB
    u16*      WinTb = (u16*)(ws + off);      off += (size_t)HH*KIN*2;     //   0.2 MB
    u16*      Xbuf  = (u16*)(ws + off);      off += (size_t)MTOT*HH*2;    //  26.2 MB
    _Float16* xw    = (_Float16*)(ws + off); off += (size_t)MTOT*G4*2;    // 104.9 MB
    u16*      Wihb  = (u16*)(ws + off);      off += (size_t)2*G4*HH*2;    //   4.2 MB
    u16*      Whhb  = (u16*)(ws + off);      off += (size_t)2*G4*HH*2;    //   4.2 MB
    u64*      h0A   = (u64*)(ws + off);      off += (size_t)BB*HH*2;
    u64*      h0B   = (u64*)(ws + off);      off += (size_t)BB*HH*2;
    u64*      h1A   = (u64*)(ws + off);      off += (size_t)BB*HH*2;
    u64*      h1B   = (u64*)(ws + off);      off += (size_t)BB*HH*2;
    u64*      x0r   = (u64*)(ws + off);      off += (size_t)4*BB*HH*2;    //   1.0 MB
    int*      bar   = (int*)(ws + off);      off += 2*4*GRPB*16*4;        //  16 KB
    (void)off; (void)ws_size;

    // weight prep (bf16 once)
    PredictionModel_58841051955204_kernel<<<384, 256, 0, stream>>>(Win, WinTb);
    k_cvt<<<8192, 256, 0, stream>>>(Wih, Wihb, 2*G4*HH);
    k_cvt<<<8192, 256, 0, stream>>>(Whh, Whhb, 2*G4*HH);

    k_feat<<<1600, 256, 0, stream>>>(x, smean, sscale, emb, feat);
    // h0 input = relu(feat @ W_in + b_in) -> Xbuf (bf16)
    k_gemm<<<dim3(400, 2), 256, 0, stream>>>(feat, KIN, WinTb, KIN, bin, (const float*)0,
                                             Xbuf, HH, 6, 1, 0);
    // xw (layer 0 only) = Xbuf @ Wih_0^T + bih_0 + bhh_0 -> fp16
    k_gemm<<<dim3(400, 8), 256, 0, stream>>>(Xbuf, HH, Wihb, HH, bih, bhh,
                                             xw, G4, 16, 0, 1);
    k_zcnt<<<16, 256, 0, stream>>>(bar);
    // fused both-layer recurrence (layer-1 absorbs its Wih GEMM in-kernel)
    k_rec2<<<256, 256, 131072, stream>>>(Whhb, Wihb + (size_t)G4*HH, xw, bih, bhh,
                                         h0A, h0B, x0r, h1A, h1B, bar);
    // T=100 even: layer-1 t=99 (odd) stores to h1A; heads write fp32 d_out
    k_heads<<<256, 256, 0, stream>>>((const u16*)h1A, Wout, bout, Wcls, bcls, (float*)d_out);
}